// Round 8
// baseline (1253.293 us; speedup 1.0000x reference)
//
#include <hip/hip_runtime.h>

#define NSITES 64
#define CHI 64
#define BATCH 32768
#define LPAD 66          // L row stride in doubles

typedef double d4 __attribute__((ext_vector_type(4)));

// 32 cycles of guaranteed spacing between MFMA result writes and VALU reads,
// pinned so the compiler cannot move register-only MFMAs across (rule #18).
#define MFMA_HAZARD_FENCE() do {                                    \
    __builtin_amdgcn_sched_barrier(0);                              \
    asm volatile("s_nop 7\n\ts_nop 7\n\ts_nop 7\n\ts_nop 7" :::);   \
    __builtin_amdgcn_sched_barrier(0);                              \
} while (0)

// ============================================================================
// Kernel 1: per-site Householder QR (LAPACK dgeqrf/dorgqr convention), f64.
// UNCHANGED from rounds 3/4 (passing + replay-stable; A must stay bit-identical).
// ============================================================================
__global__ __launch_bounds__(512) void qr_site_kernel(
    const float* __restrict__ W, double* __restrict__ A8)
{
    __shared__ double M[128][65];
    __shared__ double wpart[8][64];
    __shared__ double tauS[64];
    __shared__ double redS[2];
    __shared__ double vcol[136];

    const int i   = blockIdx.x;
    const int tid = threadIdx.x;

    for (int idx = tid; idx < 8192; idx += 512) {
        int l = idx >> 7, sr = idx & 127;
        M[sr][l] = (double)W[i * 8192 + idx];
    }
    __syncthreads();

    const int jf = tid & 63;
    const int gf = tid >> 6;
    const int r0 = gf * 16;

    for (int k = 0; k < 64; ++k) {
        const double alpha = M[k][k];
        double v2 = 0.0;
        if (tid < 128) { double xv = (tid > k) ? M[tid][k] : 0.0; v2 = xv * xv; }
        #pragma unroll
        for (int off = 32; off; off >>= 1) v2 += __shfl_down(v2, off, 64);
        if (tid < 128 && (tid & 63) == 0) redS[tid >> 6] = v2;
        __syncthreads();
        const double xnorm2 = redS[0] + redS[1];

        double beta, tk;
        if (xnorm2 == 0.0) { beta = alpha; tk = 0.0; }
        else {
            double nrm = sqrt(alpha * alpha + xnorm2);
            beta = (alpha >= 0.0) ? -nrm : nrm;
            tk   = (beta - alpha) / beta;
        }
        const double sc = (tk != 0.0) ? (1.0 / (alpha - beta)) : 0.0;
        if (tid < 128 && tid > k && tk != 0.0) M[tid][k] *= sc;
        if (tid == 0) tauS[k] = tk;
        __syncthreads();

        double part = 0.0;
        if (jf > k) {
            #pragma unroll 4
            for (int m = 0; m < 16; ++m) {
                int rr = r0 + m;
                double vr = (rr > k) ? M[rr][k] : ((rr == k) ? 1.0 : 0.0);
                part = fma(vr, M[rr][jf], part);
            }
        }
        wpart[gf][jf] = part;
        __syncthreads();
        if (jf > k) {
            double wj = tauS[k] * (wpart[0][jf] + wpart[1][jf] + wpart[2][jf] + wpart[3][jf]
                                 + wpart[4][jf] + wpart[5][jf] + wpart[6][jf] + wpart[7][jf]);
            #pragma unroll 4
            for (int m = 0; m < 16; ++m) {
                int rr = r0 + m;
                double vr = (rr > k) ? M[rr][k] : ((rr == k) ? 1.0 : 0.0);
                M[rr][jf] = fma(-vr, wj, M[rr][jf]);
            }
        }
        __syncthreads();
    }

    const int jq = tid >> 3;
    const int qq = tid & 7;
    double E[16];
    #pragma unroll
    for (int m = 0; m < 16; ++m) E[m] = ((qq * 16 + m) == jq) ? 1.0 : 0.0;

    for (int k = 63; k >= 0; --k) {
        if (tid < 128) {
            double val = (tid > k) ? M[tid][k] : ((tid == k) ? 1.0 : 0.0);
            vcol[tid + (tid >> 4)] = val;
        }
        __syncthreads();
        const double tk = tauS[k];
        double part = 0.0;
        #pragma unroll
        for (int m = 0; m < 16; ++m) {
            int rr = qq * 16 + m;
            part = fma(vcol[rr + qq], E[m], part);
        }
        part += __shfl_xor(part, 1, 64);
        part += __shfl_xor(part, 2, 64);
        part += __shfl_xor(part, 4, 64);
        const double wj = tk * part;
        #pragma unroll
        for (int m = 0; m < 16; ++m) {
            int rr = qq * 16 + m;
            E[m] = fma(-vcol[rr + qq], wj, E[m]);
        }
        __syncthreads();
    }

    double* dst = A8 + (size_t)i * 8192 + jq * 128 + qq * 16;
    #pragma unroll
    for (int m = 0; m < 16; ++m) dst[m] = E[m];
}

// ============================================================================
// Kernel 2: sampling via f64 MFMA GEMM per site (round-7 datapath, replay-
// stable with hazard fences) with __launch_bounds__(512, 2): VGPR pool 256
// (round-7's (512,1) made the compiler pick a 128-VGPR budget -> prefetch
// regs spilled to scratch: FETCH 686 MB / WRITE 1.19 GB).
// ============================================================================
#define MFMA_ROW(bp, a)                                                   \
    c0 = __builtin_amdgcn_mfma_f64_16x16x4f64((a), (bp)[  0], c0, 0,0,0); \
    c1 = __builtin_amdgcn_mfma_f64_16x16x4f64((a), (bp)[ 16], c1, 0,0,0); \
    c2 = __builtin_amdgcn_mfma_f64_16x16x4f64((a), (bp)[ 32], c2, 0,0,0); \
    c3 = __builtin_amdgcn_mfma_f64_16x16x4f64((a), (bp)[ 48], c3, 0,0,0); \
    c4 = __builtin_amdgcn_mfma_f64_16x16x4f64((a), (bp)[ 64], c4, 0,0,0); \
    c5 = __builtin_amdgcn_mfma_f64_16x16x4f64((a), (bp)[ 80], c5, 0,0,0); \
    c6 = __builtin_amdgcn_mfma_f64_16x16x4f64((a), (bp)[ 96], c6, 0,0,0); \
    c7 = __builtin_amdgcn_mfma_f64_16x16x4f64((a), (bp)[112], c7, 0,0,0);

__global__ __launch_bounds__(512, 2) void sample_kernel(
    const double* __restrict__ A8, const float* __restrict__ u,
    float* __restrict__ out)
{
    __shared__ __align__(16) double As[8192];        // A_i: [j=64][sr=128], 64 KiB
    __shared__ double Lsm[128 * LPAD];               // L: [b=128][j=64 + pad], 66 KiB

    const int tid  = threadIdx.x;
    const int w    = tid >> 6;            // wave 0..7
    const int lane = tid & 63;
    const int g    = lane >> 4;           // 0..3
    const int r    = lane & 15;           // 0..15
    const int ubase = blockIdx.x * 128 + 16 * w;   // strip's first global batch

    // ---- layout probe (register-only, once) ----
    d4 zp = {0.0, 0.0, 0.0, 0.0};
    const d4 rowP = __builtin_amdgcn_mfma_f64_16x16x4f64((g == 0) ? (double)r : 0.0, 1.0, zp, 0, 0, 0);
    const d4 colP = __builtin_amdgcn_mfma_f64_16x16x4f64((g == 0) ? 1.0 : 0.0, (double)r, zp, 0, 0, 0);
    MFMA_HAZARD_FENCE();
    const int row0 = (int)(rowP.x + 0.5), row1 = (int)(rowP.y + 0.5);
    const int row2 = (int)(rowP.z + 0.5), row3 = (int)(rowP.w + 0.5);
    const int col0 = (int)(colP.x + 0.5), col1 = (int)(colP.y + 0.5);
    const int col2 = (int)(colP.z + 0.5), col3 = (int)(colP.w + 0.5);

    // init L = e_0: lane (g,r) initializes row 16w+r, cols g, g+4, ...
    for (int j = g; j < 64; j += 4)
        Lsm[(16 * w + r) * LPAD + j] = (j == 0) ? 1.0 : 0.0;

    {   // stage site 0
        const double2* s2 = (const double2*)A8;
        double2* a2 = (double2*)As;
        #pragma unroll
        for (int q = 0; q < 8; ++q) a2[q * 512 + tid] = s2[q * 512 + tid];
    }
    __syncthreads();

    float* probOut = out + (size_t)BATCH * (NSITES * 2);

    for (int site = 0; site < NSITES; ++site) {
        // prefetch next site's A into named regs (hidden under MFMA phase)
        const double2* nx = (const double2*)(A8 +
            (size_t)((site < NSITES - 1) ? site + 1 : site) * 8192);
        const double2 pr0 = nx[0 * 512 + tid], pr1 = nx[1 * 512 + tid];
        const double2 pr2 = nx[2 * 512 + tid], pr3 = nx[3 * 512 + tid];
        const double2 pr4 = nx[4 * 512 + tid], pr5 = nx[5 * 512 + tid];
        const double2 pr6 = nx[6 * 512 + tid], pr7 = nx[7 * 512 + tid];
        // u values for this lane's (probed) batch rows
        const float u0 = u[(size_t)(ubase + row0) * NSITES + site];
        const float u1 = u[(size_t)(ubase + row1) * NSITES + site];
        const float u2 = u[(size_t)(ubase + row2) * NSITES + site];
        const float u3 = u[(size_t)(ubase + row3) * NSITES + site];

        d4 c0 = {0.0, 0.0, 0.0, 0.0}, c1 = c0, c2 = c0, c3 = c0;
        d4 c4 = c0, c5 = c0, c6 = c0, c7 = c0;

        const double* Lp = Lsm + (16 * w + r) * LPAD + g;   // A-op: L[16w+r][g+4kk]
        const double* Ap = As + g * 128 + r;                // B-op: A[g+4kk][16t+r]
        #pragma unroll
        for (int kk = 0; kk < 16; ++kk) {
            const double a = Lp[4 * kk];
            const double* bp = Ap + kk * 512;
            MFMA_ROW(bp, a)
        }
        MFMA_HAZARD_FENCE();              // settle all c-reg writes before VALU reads

        // p0 per row: tiles 0..3 are the s=0 half (col-permutation-invariant);
        // xor-butterfly over the 16-lane group (row map is r-independent).
        double P0 = fma(c3.x, c3.x, fma(c2.x, c2.x, fma(c1.x, c1.x, c0.x * c0.x)));
        double P1 = fma(c3.y, c3.y, fma(c2.y, c2.y, fma(c1.y, c1.y, c0.y * c0.y)));
        double P2 = fma(c3.z, c3.z, fma(c2.z, c2.z, fma(c1.z, c1.z, c0.z * c0.z)));
        double P3 = fma(c3.w, c3.w, fma(c2.w, c2.w, fma(c1.w, c1.w, c0.w * c0.w)));
        #pragma unroll
        for (int m = 1; m <= 8; m <<= 1) {
            P0 += __shfl_xor(P0, m, 64);
            P1 += __shfl_xor(P1, m, 64);
            P2 += __shfl_xor(P2, m, 64);
            P3 += __shfl_xor(P3, m, 64);
        }

        const bool t0 = ((double)u0 >= P0);
        const bool t1 = ((double)u1 >= P1);
        const bool t2 = ((double)u2 >= P2);
        const bool t3 = ((double)u3 >= P3);
        const double s0 = t0 ? (1.0 - P0) : P0;   // p0+p1==1 by isometry
        const double s1 = t1 ? (1.0 - P1) : P1;
        const double s2 = t2 ? (1.0 - P2) : P2;
        const double s3 = t3 ? (1.0 - P3) : P3;
        const double i0 = 1.0 / sqrt(s0);
        const double i1 = 1.0 / sqrt(s1);
        const double i2 = 1.0 / sqrt(s2);
        const double i3 = 1.0 / sqrt(s3);

        // chosen T -> new L rows at probed (row,col) (own strip; barrier-ordered
        // vs next site's reads by the two __syncthreads below)
        double* LwB = Lsm + (16 * w) * LPAD;
        LwB[row0 * LPAD +  0 + col0] = (t0 ? c4.x : c0.x) * i0;
        LwB[row0 * LPAD + 16 + col0] = (t0 ? c5.x : c1.x) * i0;
        LwB[row0 * LPAD + 32 + col0] = (t0 ? c6.x : c2.x) * i0;
        LwB[row0 * LPAD + 48 + col0] = (t0 ? c7.x : c3.x) * i0;
        LwB[row1 * LPAD +  0 + col1] = (t1 ? c4.y : c0.y) * i1;
        LwB[row1 * LPAD + 16 + col1] = (t1 ? c5.y : c1.y) * i1;
        LwB[row1 * LPAD + 32 + col1] = (t1 ? c6.y : c2.y) * i1;
        LwB[row1 * LPAD + 48 + col1] = (t1 ? c7.y : c3.y) * i1;
        LwB[row2 * LPAD +  0 + col2] = (t2 ? c4.z : c0.z) * i2;
        LwB[row2 * LPAD + 16 + col2] = (t2 ? c5.z : c1.z) * i2;
        LwB[row2 * LPAD + 32 + col2] = (t2 ? c6.z : c2.z) * i2;
        LwB[row2 * LPAD + 48 + col2] = (t2 ? c7.z : c3.z) * i2;
        LwB[row3 * LPAD +  0 + col3] = (t3 ? c4.w : c0.w) * i3;
        LwB[row3 * LPAD + 16 + col3] = (t3 ? c5.w : c1.w) * i3;
        LwB[row3 * LPAD + 32 + col3] = (t3 ? c6.w : c2.w) * i3;
        LwB[row3 * LPAD + 48 + col3] = (t3 ? c7.w : c3.w) * i3;

        if (r == 0) {   // rows {row0..row3} per g partition 0..15 -> full cover
            probOut[(size_t)(ubase + row0) * NSITES + site] = (float)s0;
            probOut[(size_t)(ubase + row1) * NSITES + site] = (float)s1;
            probOut[(size_t)(ubase + row2) * NSITES + site] = (float)s2;
            probOut[(size_t)(ubase + row3) * NSITES + site] = (float)s3;
            *(float2*)(out + (size_t)(ubase + row0) * 128 + site * 2) = make_float2(t0 ? 1.f : 0.f, t0 ? 0.f : 1.f);
            *(float2*)(out + (size_t)(ubase + row1) * 128 + site * 2) = make_float2(t1 ? 1.f : 0.f, t1 ? 0.f : 1.f);
            *(float2*)(out + (size_t)(ubase + row2) * 128 + site * 2) = make_float2(t2 ? 1.f : 0.f, t2 ? 0.f : 1.f);
            *(float2*)(out + (size_t)(ubase + row3) * 128 + site * 2) = make_float2(t3 ? 1.f : 0.f, t3 ? 0.f : 1.f);
        }

        __syncthreads();                  // all waves done reading As + L writes drained
        if (site < NSITES - 1) {
            double2* a2 = (double2*)As;
            a2[0 * 512 + tid] = pr0; a2[1 * 512 + tid] = pr1;
            a2[2 * 512 + tid] = pr2; a2[3 * 512 + tid] = pr3;
            a2[4 * 512 + tid] = pr4; a2[5 * 512 + tid] = pr5;
            a2[6 * 512 + tid] = pr6; a2[7 * 512 + tid] = pr7;
        }
        __syncthreads();
    }
}

extern "C" void kernel_launch(void* const* d_in, const int* in_sizes, int n_in,
                              void* d_out, int out_size, void* d_ws, size_t ws_size,
                              hipStream_t stream)
{
    const float* W = (const float*)d_in[0];   // [64,64,2,64] f32
    const float* u = (const float*)d_in[1];   // [32768,64] f32
    float* out = (float*)d_out;               // s_hat [B,64,2] then prob [B,64]
    double* A8 = (double*)d_ws;               // isometrized A, f64, 4 MiB

    hipLaunchKernelGGL(qr_site_kernel, dim3(NSITES), dim3(512), 0, stream, W, A8);
    hipLaunchKernelGGL(sample_kernel, dim3(256), dim3(512), 0, stream, A8, u, out);
}

// Round 9
// 990.737 us; speedup vs baseline: 1.2650x; 1.2650x over previous
//
#include <hip/hip_runtime.h>

#define NSITES 64
#define CHI 64
#define BATCH 32768
#define LPAD 66          // L row stride in doubles

typedef double d4 __attribute__((ext_vector_type(4)));

// 32 cycles of guaranteed spacing between MFMA result writes and VALU reads,
// pinned so the compiler cannot move register-only MFMAs across (rule #18).
#define MFMA_HAZARD_FENCE() do {                                    \
    __builtin_amdgcn_sched_barrier(0);                              \
    asm volatile("s_nop 7\n\ts_nop 7\n\ts_nop 7\n\ts_nop 7" :::);   \
    __builtin_amdgcn_sched_barrier(0);                              \
} while (0)

// ============================================================================
// Kernel 1: per-site Householder QR (LAPACK dgeqrf/dorgqr convention), f64.
// UNCHANGED from rounds 3/4 (passing + replay-stable; A must stay bit-identical).
// ============================================================================
__global__ __launch_bounds__(512) void qr_site_kernel(
    const float* __restrict__ W, double* __restrict__ A8)
{
    __shared__ double M[128][65];
    __shared__ double wpart[8][64];
    __shared__ double tauS[64];
    __shared__ double redS[2];
    __shared__ double vcol[136];

    const int i   = blockIdx.x;
    const int tid = threadIdx.x;

    for (int idx = tid; idx < 8192; idx += 512) {
        int l = idx >> 7, sr = idx & 127;
        M[sr][l] = (double)W[i * 8192 + idx];
    }
    __syncthreads();

    const int jf = tid & 63;
    const int gf = tid >> 6;
    const int r0 = gf * 16;

    for (int k = 0; k < 64; ++k) {
        const double alpha = M[k][k];
        double v2 = 0.0;
        if (tid < 128) { double xv = (tid > k) ? M[tid][k] : 0.0; v2 = xv * xv; }
        #pragma unroll
        for (int off = 32; off; off >>= 1) v2 += __shfl_down(v2, off, 64);
        if (tid < 128 && (tid & 63) == 0) redS[tid >> 6] = v2;
        __syncthreads();
        const double xnorm2 = redS[0] + redS[1];

        double beta, tk;
        if (xnorm2 == 0.0) { beta = alpha; tk = 0.0; }
        else {
            double nrm = sqrt(alpha * alpha + xnorm2);
            beta = (alpha >= 0.0) ? -nrm : nrm;
            tk   = (beta - alpha) / beta;
        }
        const double sc = (tk != 0.0) ? (1.0 / (alpha - beta)) : 0.0;
        if (tid < 128 && tid > k && tk != 0.0) M[tid][k] *= sc;
        if (tid == 0) tauS[k] = tk;
        __syncthreads();

        double part = 0.0;
        if (jf > k) {
            #pragma unroll 4
            for (int m = 0; m < 16; ++m) {
                int rr = r0 + m;
                double vr = (rr > k) ? M[rr][k] : ((rr == k) ? 1.0 : 0.0);
                part = fma(vr, M[rr][jf], part);
            }
        }
        wpart[gf][jf] = part;
        __syncthreads();
        if (jf > k) {
            double wj = tauS[k] * (wpart[0][jf] + wpart[1][jf] + wpart[2][jf] + wpart[3][jf]
                                 + wpart[4][jf] + wpart[5][jf] + wpart[6][jf] + wpart[7][jf]);
            #pragma unroll 4
            for (int m = 0; m < 16; ++m) {
                int rr = r0 + m;
                double vr = (rr > k) ? M[rr][k] : ((rr == k) ? 1.0 : 0.0);
                M[rr][jf] = fma(-vr, wj, M[rr][jf]);
            }
        }
        __syncthreads();
    }

    const int jq = tid >> 3;
    const int qq = tid & 7;
    double E[16];
    #pragma unroll
    for (int m = 0; m < 16; ++m) E[m] = ((qq * 16 + m) == jq) ? 1.0 : 0.0;

    for (int k = 63; k >= 0; --k) {
        if (tid < 128) {
            double val = (tid > k) ? M[tid][k] : ((tid == k) ? 1.0 : 0.0);
            vcol[tid + (tid >> 4)] = val;
        }
        __syncthreads();
        const double tk = tauS[k];
        double part = 0.0;
        #pragma unroll
        for (int m = 0; m < 16; ++m) {
            int rr = qq * 16 + m;
            part = fma(vcol[rr + qq], E[m], part);
        }
        part += __shfl_xor(part, 1, 64);
        part += __shfl_xor(part, 2, 64);
        part += __shfl_xor(part, 4, 64);
        const double wj = tk * part;
        #pragma unroll
        for (int m = 0; m < 16; ++m) {
            int rr = qq * 16 + m;
            E[m] = fma(-vcol[rr + qq], wj, E[m]);
        }
        __syncthreads();
    }

    double* dst = A8 + (size_t)i * 8192 + jq * 128 + qq * 16;
    #pragma unroll
    for (int m = 0; m < 16; ++m) dst[m] = E[m];
}

// ============================================================================
// Kernel 2: sampling via f64 MFMA GEMM per site (round-8 datapath, replay-
// stable). CHANGE vs round 8: the register prefetch of next site's A is
// REMOVED — 32 VGPRs live across the 128-MFMA loop were the spill source
// (FETCH 686 MB / WRITE 1.19 GB scratch traffic at the compiler's 128-VGPR
// budget). A is now staged between the two bottom barriers with transient
// registers (round-2 pattern): ~500 cyc exposed per site (~16 us total) vs
// ~350 us spill tax.
// ============================================================================
#define MFMA_ROW(bp, a)                                                   \
    c0 = __builtin_amdgcn_mfma_f64_16x16x4f64((a), (bp)[  0], c0, 0,0,0); \
    c1 = __builtin_amdgcn_mfma_f64_16x16x4f64((a), (bp)[ 16], c1, 0,0,0); \
    c2 = __builtin_amdgcn_mfma_f64_16x16x4f64((a), (bp)[ 32], c2, 0,0,0); \
    c3 = __builtin_amdgcn_mfma_f64_16x16x4f64((a), (bp)[ 48], c3, 0,0,0); \
    c4 = __builtin_amdgcn_mfma_f64_16x16x4f64((a), (bp)[ 64], c4, 0,0,0); \
    c5 = __builtin_amdgcn_mfma_f64_16x16x4f64((a), (bp)[ 80], c5, 0,0,0); \
    c6 = __builtin_amdgcn_mfma_f64_16x16x4f64((a), (bp)[ 96], c6, 0,0,0); \
    c7 = __builtin_amdgcn_mfma_f64_16x16x4f64((a), (bp)[112], c7, 0,0,0);

__global__ __launch_bounds__(512, 2) void sample_kernel(
    const double* __restrict__ A8, const float* __restrict__ u,
    float* __restrict__ out)
{
    __shared__ __align__(16) double As[8192];        // A_i: [j=64][sr=128], 64 KiB
    __shared__ double Lsm[128 * LPAD];               // L: [b=128][j=64 + pad], 66 KiB

    const int tid  = threadIdx.x;
    const int w    = tid >> 6;            // wave 0..7
    const int lane = tid & 63;
    const int g    = lane >> 4;           // 0..3
    const int r    = lane & 15;           // 0..15
    const int ubase = blockIdx.x * 128 + 16 * w;   // strip's first global batch

    // ---- layout probe (register-only, once) ----
    d4 zp = {0.0, 0.0, 0.0, 0.0};
    const d4 rowP = __builtin_amdgcn_mfma_f64_16x16x4f64((g == 0) ? (double)r : 0.0, 1.0, zp, 0, 0, 0);
    const d4 colP = __builtin_amdgcn_mfma_f64_16x16x4f64((g == 0) ? 1.0 : 0.0, (double)r, zp, 0, 0, 0);
    MFMA_HAZARD_FENCE();
    const int row0 = (int)(rowP.x + 0.5), row1 = (int)(rowP.y + 0.5);
    const int row2 = (int)(rowP.z + 0.5), row3 = (int)(rowP.w + 0.5);
    const int col0 = (int)(colP.x + 0.5), col1 = (int)(colP.y + 0.5);
    const int col2 = (int)(colP.z + 0.5), col3 = (int)(colP.w + 0.5);

    // init L = e_0: lane (g,r) initializes row 16w+r, cols g, g+4, ...
    for (int j = g; j < 64; j += 4)
        Lsm[(16 * w + r) * LPAD + j] = (j == 0) ? 1.0 : 0.0;

    {   // stage site 0
        const double2* s2 = (const double2*)A8;
        double2* a2 = (double2*)As;
        #pragma unroll
        for (int q = 0; q < 8; ++q) a2[q * 512 + tid] = s2[q * 512 + tid];
    }
    __syncthreads();

    float* probOut = out + (size_t)BATCH * (NSITES * 2);

    for (int site = 0; site < NSITES; ++site) {
        // u values for this lane's (probed) batch rows
        const float u0 = u[(size_t)(ubase + row0) * NSITES + site];
        const float u1 = u[(size_t)(ubase + row1) * NSITES + site];
        const float u2 = u[(size_t)(ubase + row2) * NSITES + site];
        const float u3 = u[(size_t)(ubase + row3) * NSITES + site];

        d4 c0 = {0.0, 0.0, 0.0, 0.0}, c1 = c0, c2 = c0, c3 = c0;
        d4 c4 = c0, c5 = c0, c6 = c0, c7 = c0;

        const double* Lp = Lsm + (16 * w + r) * LPAD + g;   // A-op: L[16w+r][g+4kk]
        const double* Ap = As + g * 128 + r;                // B-op: A[g+4kk][16t+r]
        #pragma unroll
        for (int kk = 0; kk < 16; ++kk) {
            const double a = Lp[4 * kk];
            const double* bp = Ap + kk * 512;
            MFMA_ROW(bp, a)
        }
        MFMA_HAZARD_FENCE();              // settle all c-reg writes before VALU reads

        // p0 per row: tiles 0..3 are the s=0 half (col-permutation-invariant);
        // xor-butterfly over the 16-lane group (row map is r-independent).
        double P0 = fma(c3.x, c3.x, fma(c2.x, c2.x, fma(c1.x, c1.x, c0.x * c0.x)));
        double P1 = fma(c3.y, c3.y, fma(c2.y, c2.y, fma(c1.y, c1.y, c0.y * c0.y)));
        double P2 = fma(c3.z, c3.z, fma(c2.z, c2.z, fma(c1.z, c1.z, c0.z * c0.z)));
        double P3 = fma(c3.w, c3.w, fma(c2.w, c2.w, fma(c1.w, c1.w, c0.w * c0.w)));
        #pragma unroll
        for (int m = 1; m <= 8; m <<= 1) {
            P0 += __shfl_xor(P0, m, 64);
            P1 += __shfl_xor(P1, m, 64);
            P2 += __shfl_xor(P2, m, 64);
            P3 += __shfl_xor(P3, m, 64);
        }

        const bool t0 = ((double)u0 >= P0);
        const bool t1 = ((double)u1 >= P1);
        const bool t2 = ((double)u2 >= P2);
        const bool t3 = ((double)u3 >= P3);
        const double s0 = t0 ? (1.0 - P0) : P0;   // p0+p1==1 by isometry
        const double s1 = t1 ? (1.0 - P1) : P1;
        const double s2 = t2 ? (1.0 - P2) : P2;
        const double s3 = t3 ? (1.0 - P3) : P3;
        const double i0 = 1.0 / sqrt(s0);
        const double i1 = 1.0 / sqrt(s1);
        const double i2 = 1.0 / sqrt(s2);
        const double i3 = 1.0 / sqrt(s3);

        // chosen T -> new L rows at probed (row,col) (own strip; same-wave
        // program order vs next site's reads)
        double* LwB = Lsm + (16 * w) * LPAD;
        LwB[row0 * LPAD +  0 + col0] = (t0 ? c4.x : c0.x) * i0;
        LwB[row0 * LPAD + 16 + col0] = (t0 ? c5.x : c1.x) * i0;
        LwB[row0 * LPAD + 32 + col0] = (t0 ? c6.x : c2.x) * i0;
        LwB[row0 * LPAD + 48 + col0] = (t0 ? c7.x : c3.x) * i0;
        LwB[row1 * LPAD +  0 + col1] = (t1 ? c4.y : c0.y) * i1;
        LwB[row1 * LPAD + 16 + col1] = (t1 ? c5.y : c1.y) * i1;
        LwB[row1 * LPAD + 32 + col1] = (t1 ? c6.y : c2.y) * i1;
        LwB[row1 * LPAD + 48 + col1] = (t1 ? c7.y : c3.y) * i1;
        LwB[row2 * LPAD +  0 + col2] = (t2 ? c4.z : c0.z) * i2;
        LwB[row2 * LPAD + 16 + col2] = (t2 ? c5.z : c1.z) * i2;
        LwB[row2 * LPAD + 32 + col2] = (t2 ? c6.z : c2.z) * i2;
        LwB[row2 * LPAD + 48 + col2] = (t2 ? c7.z : c3.z) * i2;
        LwB[row3 * LPAD +  0 + col3] = (t3 ? c4.w : c0.w) * i3;
        LwB[row3 * LPAD + 16 + col3] = (t3 ? c5.w : c1.w) * i3;
        LwB[row3 * LPAD + 32 + col3] = (t3 ? c6.w : c2.w) * i3;
        LwB[row3 * LPAD + 48 + col3] = (t3 ? c7.w : c3.w) * i3;

        if (r == 0) {   // rows {row0..row3} per g partition 0..15 -> full cover
            probOut[(size_t)(ubase + row0) * NSITES + site] = (float)s0;
            probOut[(size_t)(ubase + row1) * NSITES + site] = (float)s1;
            probOut[(size_t)(ubase + row2) * NSITES + site] = (float)s2;
            probOut[(size_t)(ubase + row3) * NSITES + site] = (float)s3;
            *(float2*)(out + (size_t)(ubase + row0) * 128 + site * 2) = make_float2(t0 ? 1.f : 0.f, t0 ? 0.f : 1.f);
            *(float2*)(out + (size_t)(ubase + row1) * 128 + site * 2) = make_float2(t1 ? 1.f : 0.f, t1 ? 0.f : 1.f);
            *(float2*)(out + (size_t)(ubase + row2) * 128 + site * 2) = make_float2(t2 ? 1.f : 0.f, t2 ? 0.f : 1.f);
            *(float2*)(out + (size_t)(ubase + row3) * 128 + site * 2) = make_float2(t3 ? 1.f : 0.f, t3 ? 0.f : 1.f);
        }

        __syncthreads();                  // all waves done reading As this site
        if (site < NSITES - 1) {
            // stage next site's A with TRANSIENT registers (no long live ranges)
            const double2* s2 = (const double2*)(A8 + (size_t)(site + 1) * 8192);
            double2* a2 = (double2*)As;
            #pragma unroll
            for (int q = 0; q < 8; ++q) a2[q * 512 + tid] = s2[q * 512 + tid];
        }
        __syncthreads();
    }
}

extern "C" void kernel_launch(void* const* d_in, const int* in_sizes, int n_in,
                              void* d_out, int out_size, void* d_ws, size_t ws_size,
                              hipStream_t stream)
{
    const float* W = (const float*)d_in[0];   // [64,64,2,64] f32
    const float* u = (const float*)d_in[1];   // [32768,64] f32
    float* out = (float*)d_out;               // s_hat [B,64,2] then prob [B,64]
    double* A8 = (double*)d_ws;               // isometrized A, f64, 4 MiB

    hipLaunchKernelGGL(qr_site_kernel, dim3(NSITES), dim3(512), 0, stream, W, A8);
    hipLaunchKernelGGL(sample_kernel, dim3(256), dim3(512), 0, stream, A8, u, out);
}

// Round 10
// 814.892 us; speedup vs baseline: 1.5380x; 1.2158x over previous
//
#include <hip/hip_runtime.h>

#define NSITES 64
#define CHI 64
#define BATCH 32768
#define LPAD 66          // L row stride in doubles

typedef double d4 __attribute__((ext_vector_type(4)));

// 32 cycles of guaranteed spacing between MFMA result writes and VALU reads,
// pinned so the compiler cannot move register-only MFMAs across (rule #18).
#define MFMA_HAZARD_FENCE() do {                                    \
    __builtin_amdgcn_sched_barrier(0);                              \
    asm volatile("s_nop 7\n\ts_nop 7\n\ts_nop 7\n\ts_nop 7" :::);   \
    __builtin_amdgcn_sched_barrier(0);                              \
} while (0)

// ============================================================================
// Kernel 1: per-site Householder QR (LAPACK dgeqrf/dorgqr convention), f64.
// UNCHANGED from rounds 3/4 (passing + replay-stable; A must stay bit-identical).
// ============================================================================
__global__ __launch_bounds__(512) void qr_site_kernel(
    const float* __restrict__ W, double* __restrict__ A8)
{
    __shared__ double M[128][65];
    __shared__ double wpart[8][64];
    __shared__ double tauS[64];
    __shared__ double redS[2];
    __shared__ double vcol[136];

    const int i   = blockIdx.x;
    const int tid = threadIdx.x;

    for (int idx = tid; idx < 8192; idx += 512) {
        int l = idx >> 7, sr = idx & 127;
        M[sr][l] = (double)W[i * 8192 + idx];
    }
    __syncthreads();

    const int jf = tid & 63;
    const int gf = tid >> 6;
    const int r0 = gf * 16;

    for (int k = 0; k < 64; ++k) {
        const double alpha = M[k][k];
        double v2 = 0.0;
        if (tid < 128) { double xv = (tid > k) ? M[tid][k] : 0.0; v2 = xv * xv; }
        #pragma unroll
        for (int off = 32; off; off >>= 1) v2 += __shfl_down(v2, off, 64);
        if (tid < 128 && (tid & 63) == 0) redS[tid >> 6] = v2;
        __syncthreads();
        const double xnorm2 = redS[0] + redS[1];

        double beta, tk;
        if (xnorm2 == 0.0) { beta = alpha; tk = 0.0; }
        else {
            double nrm = sqrt(alpha * alpha + xnorm2);
            beta = (alpha >= 0.0) ? -nrm : nrm;
            tk   = (beta - alpha) / beta;
        }
        const double sc = (tk != 0.0) ? (1.0 / (alpha - beta)) : 0.0;
        if (tid < 128 && tid > k && tk != 0.0) M[tid][k] *= sc;
        if (tid == 0) tauS[k] = tk;
        __syncthreads();

        double part = 0.0;
        if (jf > k) {
            #pragma unroll 4
            for (int m = 0; m < 16; ++m) {
                int rr = r0 + m;
                double vr = (rr > k) ? M[rr][k] : ((rr == k) ? 1.0 : 0.0);
                part = fma(vr, M[rr][jf], part);
            }
        }
        wpart[gf][jf] = part;
        __syncthreads();
        if (jf > k) {
            double wj = tauS[k] * (wpart[0][jf] + wpart[1][jf] + wpart[2][jf] + wpart[3][jf]
                                 + wpart[4][jf] + wpart[5][jf] + wpart[6][jf] + wpart[7][jf]);
            #pragma unroll 4
            for (int m = 0; m < 16; ++m) {
                int rr = r0 + m;
                double vr = (rr > k) ? M[rr][k] : ((rr == k) ? 1.0 : 0.0);
                M[rr][jf] = fma(-vr, wj, M[rr][jf]);
            }
        }
        __syncthreads();
    }

    const int jq = tid >> 3;
    const int qq = tid & 7;
    double E[16];
    #pragma unroll
    for (int m = 0; m < 16; ++m) E[m] = ((qq * 16 + m) == jq) ? 1.0 : 0.0;

    for (int k = 63; k >= 0; --k) {
        if (tid < 128) {
            double val = (tid > k) ? M[tid][k] : ((tid == k) ? 1.0 : 0.0);
            vcol[tid + (tid >> 4)] = val;
        }
        __syncthreads();
        const double tk = tauS[k];
        double part = 0.0;
        #pragma unroll
        for (int m = 0; m < 16; ++m) {
            int rr = qq * 16 + m;
            part = fma(vcol[rr + qq], E[m], part);
        }
        part += __shfl_xor(part, 1, 64);
        part += __shfl_xor(part, 2, 64);
        part += __shfl_xor(part, 4, 64);
        const double wj = tk * part;
        #pragma unroll
        for (int m = 0; m < 16; ++m) {
            int rr = qq * 16 + m;
            E[m] = fma(-vcol[rr + qq], wj, E[m]);
        }
        __syncthreads();
    }

    double* dst = A8 + (size_t)i * 8192 + jq * 128 + qq * 16;
    #pragma unroll
    for (int m = 0; m < 16; ++m) dst[m] = E[m];
}

// ============================================================================
// Kernel 2: sampling via f64 MFMA GEMM per site (round-9 datapath, replay-
// stable). CHANGE vs round 9: fully-hidden half-split staging —
//   kk 0..7 | issue H0 loads (16 transient VGPRs) | kk 8..15 | BAR_A |
//   ds_write H0 + issue H1 loads | epilogue | ds_write H1 | BAR_B
// (exposed staging latency ~0 vs ~1.8k cyc/site serial in round 9; r8's spill
// came from +32 regs across the WHOLE loop — here +16 across half), and
// rsqrt(double) replaces exact 1.0/sqrt (halves the renorm VALU chain;
// ~1e-15 rel perturbation vs 2.4e-7 decision gap).
// ============================================================================
#define MFMA_ROW(bp, a)                                                   \
    c0 = __builtin_amdgcn_mfma_f64_16x16x4f64((a), (bp)[  0], c0, 0,0,0); \
    c1 = __builtin_amdgcn_mfma_f64_16x16x4f64((a), (bp)[ 16], c1, 0,0,0); \
    c2 = __builtin_amdgcn_mfma_f64_16x16x4f64((a), (bp)[ 32], c2, 0,0,0); \
    c3 = __builtin_amdgcn_mfma_f64_16x16x4f64((a), (bp)[ 48], c3, 0,0,0); \
    c4 = __builtin_amdgcn_mfma_f64_16x16x4f64((a), (bp)[ 64], c4, 0,0,0); \
    c5 = __builtin_amdgcn_mfma_f64_16x16x4f64((a), (bp)[ 80], c5, 0,0,0); \
    c6 = __builtin_amdgcn_mfma_f64_16x16x4f64((a), (bp)[ 96], c6, 0,0,0); \
    c7 = __builtin_amdgcn_mfma_f64_16x16x4f64((a), (bp)[112], c7, 0,0,0);

__global__ __launch_bounds__(512, 2) void sample_kernel(
    const double* __restrict__ A8, const float* __restrict__ u,
    float* __restrict__ out)
{
    __shared__ __align__(16) double As[8192];        // A_i: [j=64][sr=128], 64 KiB
    __shared__ double Lsm[128 * LPAD];               // L: [b=128][j=64 + pad], 66 KiB

    const int tid  = threadIdx.x;
    const int w    = tid >> 6;            // wave 0..7
    const int lane = tid & 63;
    const int g    = lane >> 4;           // 0..3
    const int r    = lane & 15;           // 0..15
    const int ubase = blockIdx.x * 128 + 16 * w;   // strip's first global batch

    // ---- layout probe (register-only, once) ----
    d4 zp = {0.0, 0.0, 0.0, 0.0};
    const d4 rowP = __builtin_amdgcn_mfma_f64_16x16x4f64((g == 0) ? (double)r : 0.0, 1.0, zp, 0, 0, 0);
    const d4 colP = __builtin_amdgcn_mfma_f64_16x16x4f64((g == 0) ? 1.0 : 0.0, (double)r, zp, 0, 0, 0);
    MFMA_HAZARD_FENCE();
    const int row0 = (int)(rowP.x + 0.5), row1 = (int)(rowP.y + 0.5);
    const int row2 = (int)(rowP.z + 0.5), row3 = (int)(rowP.w + 0.5);
    const int col0 = (int)(colP.x + 0.5), col1 = (int)(colP.y + 0.5);
    const int col2 = (int)(colP.z + 0.5), col3 = (int)(colP.w + 0.5);

    // init L = e_0: lane (g,r) initializes row 16w+r, cols g, g+4, ...
    for (int j = g; j < 64; j += 4)
        Lsm[(16 * w + r) * LPAD + j] = (j == 0) ? 1.0 : 0.0;

    {   // stage site 0 (full)
        const double2* s2 = (const double2*)A8;
        double2* a2 = (double2*)As;
        #pragma unroll
        for (int q = 0; q < 8; ++q) a2[q * 512 + tid] = s2[q * 512 + tid];
    }
    __syncthreads();

    float* probOut = out + (size_t)BATCH * (NSITES * 2);

    for (int site = 0; site < NSITES; ++site) {
        // u values for this lane's (probed) batch rows
        const float u0 = u[(size_t)(ubase + row0) * NSITES + site];
        const float u1 = u[(size_t)(ubase + row1) * NSITES + site];
        const float u2 = u[(size_t)(ubase + row2) * NSITES + site];
        const float u3 = u[(size_t)(ubase + row3) * NSITES + site];

        d4 c0 = {0.0, 0.0, 0.0, 0.0}, c1 = c0, c2 = c0, c3 = c0;
        d4 c4 = c0, c5 = c0, c6 = c0, c7 = c0;

        const double* Lp = Lsm + (16 * w + r) * LPAD + g;   // A-op: L[16w+r][g+4kk]
        const double* Ap = As + g * 128 + r;                // B-op: A[g+4kk][16t+r]

        // ---- first half: kk 0..7 (reads As rows 0..31) ----
        #pragma unroll
        for (int kk = 0; kk < 8; ++kk) {
            const double a = Lp[4 * kk];
            const double* bp = Ap + kk * 512;
            MFMA_ROW(bp, a)
        }

        // issue H0 staging loads (next site rows 0..31); latency hides under
        // the second MFMA half. Only 16 VGPRs, live across half the loop.
        double2 st0, st1, st2, st3;
        if (site < NSITES - 1) {
            const double2* nx = (const double2*)(A8 + (size_t)(site + 1) * 8192);
            st0 = nx[0 * 512 + tid]; st1 = nx[1 * 512 + tid];
            st2 = nx[2 * 512 + tid]; st3 = nx[3 * 512 + tid];
        }

        // ---- second half: kk 8..15 (reads As rows 32..63) ----
        #pragma unroll
        for (int kk = 8; kk < 16; ++kk) {
            const double a = Lp[4 * kk];
            const double* bp = Ap + kk * 512;
            MFMA_ROW(bp, a)
        }

        __syncthreads();                 // BAR_A: ALL waves done reading As

        // write H0; issue H1 loads (latency hides under epilogue)
        double2 st4, st5, st6, st7;
        if (site < NSITES - 1) {
            double2* a2 = (double2*)As;
            a2[0 * 512 + tid] = st0; a2[1 * 512 + tid] = st1;
            a2[2 * 512 + tid] = st2; a2[3 * 512 + tid] = st3;
            const double2* nx = (const double2*)(A8 + (size_t)(site + 1) * 8192);
            st4 = nx[4 * 512 + tid]; st5 = nx[5 * 512 + tid];
            st6 = nx[6 * 512 + tid]; st7 = nx[7 * 512 + tid];
        }

        MFMA_HAZARD_FENCE();             // settle all c-reg writes before VALU reads

        // p0 per row: tiles 0..3 are the s=0 half (col-permutation-invariant);
        // xor-butterfly over the 16-lane group (row map is r-independent).
        double P0 = fma(c3.x, c3.x, fma(c2.x, c2.x, fma(c1.x, c1.x, c0.x * c0.x)));
        double P1 = fma(c3.y, c3.y, fma(c2.y, c2.y, fma(c1.y, c1.y, c0.y * c0.y)));
        double P2 = fma(c3.z, c3.z, fma(c2.z, c2.z, fma(c1.z, c1.z, c0.z * c0.z)));
        double P3 = fma(c3.w, c3.w, fma(c2.w, c2.w, fma(c1.w, c1.w, c0.w * c0.w)));
        #pragma unroll
        for (int m = 1; m <= 8; m <<= 1) {
            P0 += __shfl_xor(P0, m, 64);
            P1 += __shfl_xor(P1, m, 64);
            P2 += __shfl_xor(P2, m, 64);
            P3 += __shfl_xor(P3, m, 64);
        }

        const bool t0 = ((double)u0 >= P0);
        const bool t1 = ((double)u1 >= P1);
        const bool t2 = ((double)u2 >= P2);
        const bool t3 = ((double)u3 >= P3);
        const double s0 = t0 ? (1.0 - P0) : P0;   // p0+p1==1 by isometry
        const double s1 = t1 ? (1.0 - P1) : P1;
        const double s2 = t2 ? (1.0 - P2) : P2;
        const double s3 = t3 ? (1.0 - P3) : P3;
        const double i0 = rsqrt(s0);              // ~1 ulp; perturbs L ~1e-15 rel
        const double i1 = rsqrt(s1);
        const double i2 = rsqrt(s2);
        const double i3 = rsqrt(s3);

        // chosen T -> new L rows at probed (row,col) (own strip; same-wave
        // program order vs next site's reads)
        double* LwB = Lsm + (16 * w) * LPAD;
        LwB[row0 * LPAD +  0 + col0] = (t0 ? c4.x : c0.x) * i0;
        LwB[row0 * LPAD + 16 + col0] = (t0 ? c5.x : c1.x) * i0;
        LwB[row0 * LPAD + 32 + col0] = (t0 ? c6.x : c2.x) * i0;
        LwB[row0 * LPAD + 48 + col0] = (t0 ? c7.x : c3.x) * i0;
        LwB[row1 * LPAD +  0 + col1] = (t1 ? c4.y : c0.y) * i1;
        LwB[row1 * LPAD + 16 + col1] = (t1 ? c5.y : c1.y) * i1;
        LwB[row1 * LPAD + 32 + col1] = (t1 ? c6.y : c2.y) * i1;
        LwB[row1 * LPAD + 48 + col1] = (t1 ? c7.y : c3.y) * i1;
        LwB[row2 * LPAD +  0 + col2] = (t2 ? c4.z : c0.z) * i2;
        LwB[row2 * LPAD + 16 + col2] = (t2 ? c5.z : c1.z) * i2;
        LwB[row2 * LPAD + 32 + col2] = (t2 ? c6.z : c2.z) * i2;
        LwB[row2 * LPAD + 48 + col2] = (t2 ? c7.z : c3.z) * i2;
        LwB[row3 * LPAD +  0 + col3] = (t3 ? c4.w : c0.w) * i3;
        LwB[row3 * LPAD + 16 + col3] = (t3 ? c5.w : c1.w) * i3;
        LwB[row3 * LPAD + 32 + col3] = (t3 ? c6.w : c2.w) * i3;
        LwB[row3 * LPAD + 48 + col3] = (t3 ? c7.w : c3.w) * i3;

        if (r == 0) {   // rows {row0..row3} per g partition 0..15 -> full cover
            probOut[(size_t)(ubase + row0) * NSITES + site] = (float)s0;
            probOut[(size_t)(ubase + row1) * NSITES + site] = (float)s1;
            probOut[(size_t)(ubase + row2) * NSITES + site] = (float)s2;
            probOut[(size_t)(ubase + row3) * NSITES + site] = (float)s3;
            *(float2*)(out + (size_t)(ubase + row0) * 128 + site * 2) = make_float2(t0 ? 1.f : 0.f, t0 ? 0.f : 1.f);
            *(float2*)(out + (size_t)(ubase + row1) * 128 + site * 2) = make_float2(t1 ? 1.f : 0.f, t1 ? 0.f : 1.f);
            *(float2*)(out + (size_t)(ubase + row2) * 128 + site * 2) = make_float2(t2 ? 1.f : 0.f, t2 ? 0.f : 1.f);
            *(float2*)(out + (size_t)(ubase + row3) * 128 + site * 2) = make_float2(t3 ? 1.f : 0.f, t3 ? 0.f : 1.f);
        }

        // write H1 (loads issued before the epilogue; data has arrived)
        if (site < NSITES - 1) {
            double2* a2 = (double2*)As;
            a2[4 * 512 + tid] = st4; a2[5 * 512 + tid] = st5;
            a2[6 * 512 + tid] = st6; a2[7 * 512 + tid] = st7;
        }
        __syncthreads();                 // BAR_B: staged A visible to all
    }
}

extern "C" void kernel_launch(void* const* d_in, const int* in_sizes, int n_in,
                              void* d_out, int out_size, void* d_ws, size_t ws_size,
                              hipStream_t stream)
{
    const float* W = (const float*)d_in[0];   // [64,64,2,64] f32
    const float* u = (const float*)d_in[1];   // [32768,64] f32
    float* out = (float*)d_out;               // s_hat [B,64,2] then prob [B,64]
    double* A8 = (double*)d_ws;               // isometrized A, f64, 4 MiB

    hipLaunchKernelGGL(qr_site_kernel, dim3(NSITES), dim3(512), 0, stream, W, A8);
    hipLaunchKernelGGL(sample_kernel, dim3(256), dim3(512), 0, stream, A8, u, out);
}